// Round 9
// baseline (717.367 us; speedup 1.0000x reference)
//
#include <hip/hip_runtime.h>
#include <hip/hip_fp16.h>

#define NFEAT 256
#define EDIM 64

typedef float f4_t __attribute__((ext_vector_type(4)));
typedef _Float16 f16x8 __attribute__((ext_vector_type(8)));
typedef float f32x4 __attribute__((ext_vector_type(4)));

// ---------------- CSR construction ----------------

__global__ void hist_kernel(const int* __restrict__ col, int* __restrict__ deg, int E) {
  int stride = gridDim.x * blockDim.x;
  for (int e = blockIdx.x * blockDim.x + threadIdx.x; e < E; e += stride)
    atomicAdd(&deg[col[e]], 1);
}

// Block-level exclusive scan: 256 threads x 4 items = 1024 items/block.
__global__ void scan1_kernel(const int* __restrict__ deg, int* __restrict__ offs,
                             int* __restrict__ bsum, int N) {
  __shared__ int lds[256];
  int b = blockIdx.x;
  int base = b * 1024;
  int t = threadIdx.x;
  int v[4];
  int s = 0;
#pragma unroll
  for (int j = 0; j < 4; ++j) {
    int i = base + t * 4 + j;
    v[j] = (i < N) ? deg[i] : 0;
    s += v[j];
  }
  lds[t] = s;
  __syncthreads();
  int x = s;
  for (int off = 1; off < 256; off <<= 1) {
    int y = (t >= off) ? lds[t - off] : 0;
    __syncthreads();
    x += y;
    lds[t] = x;
    __syncthreads();
  }
  if (t == 255) bsum[b] = x;
  int excl = x - s;
#pragma unroll
  for (int j = 0; j < 4; ++j) {
    int i = base + t * 4 + j;
    if (i < N) offs[i] = excl;
    excl += v[j];
  }
}

// Single block exclusive scan of block sums (nb <= 256).
__global__ void scan2_kernel(int* __restrict__ bsum, int nb) {
  __shared__ int lds[256];
  int t = threadIdx.x;
  int s = (t < nb) ? bsum[t] : 0;
  lds[t] = s;
  __syncthreads();
  int x = s;
  for (int off = 1; off < 256; off <<= 1) {
    int y = (t >= off) ? lds[t - off] : 0;
    __syncthreads();
    x += y;
    lds[t] = x;
    __syncthreads();
  }
  if (t < nb) bsum[t] = x - s;  // exclusive
}

// Add block offsets, init cursor, compute deg^{-1/2}.
__global__ void finalize_kernel(int* __restrict__ offs, int* __restrict__ cursor,
                                const int* __restrict__ deg, float* __restrict__ dis,
                                const int* __restrict__ bsum, int N) {
  int stride = gridDim.x * blockDim.x;
  for (int i = blockIdx.x * blockDim.x + threadIdx.x; i < N; i += stride) {
    int o = offs[i] + bsum[i >> 10];
    offs[i] = o;
    cursor[i] = o;
    int dg = deg[i];
    dis[i] = (dg > 0) ? rsqrtf((float)dg) : 0.f;
  }
}

// Fill CSR with (src, dis[src]) pairs so prop needs no random dis gather.
__global__ void fill_kernel(const int* __restrict__ row, const int* __restrict__ col,
                            int* __restrict__ cursor, int2* __restrict__ csr,
                            const float* __restrict__ dis, int E) {
  int stride = gridDim.x * blockDim.x;
  for (int e = blockIdx.x * blockDim.x + threadIdx.x; e < E; e += stride) {
    int r = row[e];
    int c = col[e];
    int p = atomicAdd(&cursor[c], 1);
    csr[p] = make_int2(r, __float_as_int(dis[r]));
  }
}

// ---------------- Embedding GEMM via MFMA: x = fp16(X) @ fp16(W)^T + b ------
#define LDS_STRIDE 264

__global__ void __launch_bounds__(256) embed_kernel(
    const float* __restrict__ X, const float* __restrict__ W,
    const float* __restrict__ bias, __half* __restrict__ x_out, int N) {
  __shared__ _Float16 Xl[64 * LDS_STRIDE];
  __shared__ _Float16 Wl[64 * LDS_STRIDE];
  const int t = threadIdx.x;
  const int base = blockIdx.x * 64;

#pragma unroll 4
  for (int p = 0; p < 16; ++p) {
    int flat = p * 256 + t;
    int row = flat >> 6;
    int col4 = flat & 63;
    float4 wv = *reinterpret_cast<const float4*>(W + (size_t)row * NFEAT + col4 * 4);
    __half2 w01 = __floats2half2_rn(wv.x, wv.y);
    __half2 w23 = __floats2half2_rn(wv.z, wv.w);
    uint2 wp = make_uint2(*reinterpret_cast<unsigned int*>(&w01),
                          *reinterpret_cast<unsigned int*>(&w23));
    *reinterpret_cast<uint2*>(&Wl[row * LDS_STRIDE + col4 * 4]) = wp;

    int xrow = base + row;
    int xr = (xrow < N) ? xrow : (N - 1);
    float4 xv = *reinterpret_cast<const float4*>(X + (size_t)xr * NFEAT + col4 * 4);
    __half2 x01 = __floats2half2_rn(xv.x, xv.y);
    __half2 x23 = __floats2half2_rn(xv.z, xv.w);
    uint2 xp = make_uint2(*reinterpret_cast<unsigned int*>(&x01),
                          *reinterpret_cast<unsigned int*>(&x23));
    *reinterpret_cast<uint2*>(&Xl[row * LDS_STRIDE + col4 * 4]) = xp;
  }
  __syncthreads();

  const int lane = t & 63;
  const int w = t >> 6;
  const int r = lane & 15;
  const int g = lane >> 4;

  f32x4 acc[4];
#pragma unroll
  for (int n = 0; n < 4; ++n) acc[n] = (f32x4){0.f, 0.f, 0.f, 0.f};

#pragma unroll
  for (int s = 0; s < 8; ++s) {
    f16x8 a = *reinterpret_cast<const f16x8*>(&Xl[(w * 16 + r) * LDS_STRIDE + s * 32 + 8 * g]);
#pragma unroll
    for (int n = 0; n < 4; ++n) {
      f16x8 bfr = *reinterpret_cast<const f16x8*>(&Wl[(n * 16 + r) * LDS_STRIDE + s * 32 + 8 * g]);
      acc[n] = __builtin_amdgcn_mfma_f32_16x16x32_f16(a, bfr, acc[n], 0, 0, 0);
    }
  }

  float bv[4];
#pragma unroll
  for (int n = 0; n < 4; ++n) bv[n] = bias[n * 16 + r];
#pragma unroll
  for (int reg = 0; reg < 4; ++reg) {
    int node = base + w * 16 + g * 4 + reg;
    if (node < N) {
#pragma unroll
      for (int n = 0; n < 4; ++n) {
        float val = acc[n][reg] + bv[n];
        x_out[(size_t)node * EDIM + n * 16 + r] = __float2half(val);
      }
    }
  }
}

// ---------------- Propagation (gather form, no atomics) ----------------
// Wave per destination node; FOUR 16-lane quarters each process a contiguous
// slice of the dst's edge list. Lane owns 4 dims via one uint2 (8B) load.

__global__ void prop_kernel(const __half* __restrict__ x_in, __half* __restrict__ x_out,
                            __half* __restrict__ out_acc, const int* __restrict__ offs,
                            const int* __restrict__ deg, const int2* __restrict__ csr,
                            const float* __restrict__ dis, const float* __restrict__ alpha,
                            int layer, int last, int N) {
  const int lane = threadIdx.x & 63;
  const int qt = lane >> 4;
  const int s16 = lane & 15;
  int wid = (blockIdx.x * blockDim.x + threadIdx.x) >> 6;
  int nw = (gridDim.x * blockDim.x) >> 6;
  float al = alpha[layer + 1];
  float a0 = alpha[0];
  const int2 z2 = make_int2(0, 0);
  for (int c = wid; c < N; c += nw) {
    int start = offs[c];
    int cnt = deg[c];
    int cntQ = (cnt + 3) >> 2;
    int myCnt = min(cntQ, max(0, cnt - qt * cntQ));
    int myStart = start + qt * cntQ;
    float ax = 0.f, ay = 0.f, az = 0.f, aw = 0.f;
    for (int j = 0; j < cntQ; j += 4) {
      int2 e0 = (j + 0 < myCnt) ? csr[myStart + j + 0] : z2;
      int2 e1 = (j + 1 < myCnt) ? csr[myStart + j + 1] : z2;
      int2 e2 = (j + 2 < myCnt) ? csr[myStart + j + 2] : z2;
      int2 e3 = (j + 3 < myCnt) ? csr[myStart + j + 3] : z2;
      uint2 v0 = *(reinterpret_cast<const uint2*>(x_in + (size_t)e0.x * EDIM) + s16);
      uint2 v1 = *(reinterpret_cast<const uint2*>(x_in + (size_t)e1.x * EDIM) + s16);
      uint2 v2 = *(reinterpret_cast<const uint2*>(x_in + (size_t)e2.x * EDIM) + s16);
      uint2 v3 = *(reinterpret_cast<const uint2*>(x_in + (size_t)e3.x * EDIM) + s16);
      float w0 = __int_as_float(e0.y), w1 = __int_as_float(e1.y);
      float w2 = __int_as_float(e2.y), w3 = __int_as_float(e3.y);
      float2 lo, hi;
      lo = __half22float2(*reinterpret_cast<const __half2*>(&v0.x));
      hi = __half22float2(*reinterpret_cast<const __half2*>(&v0.y));
      ax = fmaf(w0, lo.x, ax); ay = fmaf(w0, lo.y, ay);
      az = fmaf(w0, hi.x, az); aw = fmaf(w0, hi.y, aw);
      lo = __half22float2(*reinterpret_cast<const __half2*>(&v1.x));
      hi = __half22float2(*reinterpret_cast<const __half2*>(&v1.y));
      ax = fmaf(w1, lo.x, ax); ay = fmaf(w1, lo.y, ay);
      az = fmaf(w1, hi.x, az); aw = fmaf(w1, hi.y, aw);
      lo = __half22float2(*reinterpret_cast<const __half2*>(&v2.x));
      hi = __half22float2(*reinterpret_cast<const __half2*>(&v2.y));
      ax = fmaf(w2, lo.x, ax); ay = fmaf(w2, lo.y, ay);
      az = fmaf(w2, hi.x, az); aw = fmaf(w2, hi.y, aw);
      lo = __half22float2(*reinterpret_cast<const __half2*>(&v3.x));
      hi = __half22float2(*reinterpret_cast<const __half2*>(&v3.y));
      ax = fmaf(w3, lo.x, ax); ay = fmaf(w3, lo.y, ay);
      az = fmaf(w3, hi.x, az); aw = fmaf(w3, hi.y, aw);
    }
    ax += __shfl_xor(ax, 16); ax += __shfl_xor(ax, 32);
    ay += __shfl_xor(ay, 16); ay += __shfl_xor(ay, 32);
    az += __shfl_xor(az, 16); az += __shfl_xor(az, 32);
    aw += __shfl_xor(aw, 16); aw += __shfl_xor(aw, 32);
    if (qt == 0) {
      float dc = dis[c];
      float vx = ax * dc, vy = ay * dc, vz = az * dc, vw = aw * dc;
      size_t base = (size_t)c * EDIM + s16 * 4;
      if (!last) {
        __half2 p01 = __floats2half2_rn(vx, vy);
        __half2 p23 = __floats2half2_rn(vz, vw);
        uint2 pk = make_uint2(*reinterpret_cast<unsigned int*>(&p01),
                              *reinterpret_cast<unsigned int*>(&p23));
        *reinterpret_cast<uint2*>(x_out + base) = pk;
      }
      float ox, oy, oz, ow;
      if (layer == 0) {
        uint2 xf = *reinterpret_cast<const uint2*>(x_in + base);
        float2 xlo = __half22float2(*reinterpret_cast<const __half2*>(&xf.x));
        float2 xhi = __half22float2(*reinterpret_cast<const __half2*>(&xf.y));
        ox = fmaf(a0, xlo.x, al * vx); oy = fmaf(a0, xlo.y, al * vy);
        oz = fmaf(a0, xhi.x, al * vz); ow = fmaf(a0, xhi.y, al * vw);
      } else {
        uint2 pv = *reinterpret_cast<const uint2*>(out_acc + base);
        float2 plo = __half22float2(*reinterpret_cast<const __half2*>(&pv.x));
        float2 phi = __half22float2(*reinterpret_cast<const __half2*>(&pv.y));
        ox = fmaf(al, vx, plo.x); oy = fmaf(al, vy, plo.y);
        oz = fmaf(al, vz, phi.x); ow = fmaf(al, vw, phi.y);
      }
      __half2 o01 = __floats2half2_rn(ox, oy);
      __half2 o23 = __floats2half2_rn(oz, ow);
      uint2 ok = make_uint2(*reinterpret_cast<unsigned int*>(&o01),
                            *reinterpret_cast<unsigned int*>(&o23));
      *reinterpret_cast<uint2*>(out_acc + base) = ok;
    }
  }
}

// ---------------- Output gather ----------------

__global__ void gatherout_kernel(const __half* __restrict__ oacc, const int* __restrict__ lsrc,
                                 const int* __restrict__ ldst, float* __restrict__ out, int L) {
  int total = L * 16;
  int stride = gridDim.x * blockDim.x;
  for (int i = blockIdx.x * blockDim.x + threadIdx.x; i < total; i += stride) {
    int l = i >> 4;
    int q = i & 15;
    int node = (q < 8) ? lsrc[l] : ldst[l];
    int qq = q & 7;
    uint4 h = *reinterpret_cast<const uint4*>(oacc + (size_t)node * EDIM + qq * 8);
    float2 a = __half22float2(*reinterpret_cast<const __half2*>(&h.x));
    float2 b = __half22float2(*reinterpret_cast<const __half2*>(&h.y));
    float2 cc = __half22float2(*reinterpret_cast<const __half2*>(&h.z));
    float2 d = __half22float2(*reinterpret_cast<const __half2*>(&h.w));
    f4_t v0 = {a.x, a.y, b.x, b.y};
    f4_t v1 = {cc.x, cc.y, d.x, d.y};
    float* dst = out + (size_t)l * 128 + q * 8;
    __builtin_nontemporal_store(v0, reinterpret_cast<f4_t*>(dst));
    __builtin_nontemporal_store(v1, reinterpret_cast<f4_t*>(dst + 4));
  }
}

// ---------------- Launch ----------------
// MEASUREMENT ROUND: prop chain launched TWICE (L0 re-inits oacc; chain is a
// pure function of xa via xa->xb->xc ping-pong) => final state identical,
// dur delta vs r8 == prop-chain cost.

extern "C" void kernel_launch(void* const* d_in, const int* in_sizes, int n_in,
                              void* d_out, int out_size, void* d_ws, size_t ws_size,
                              hipStream_t stream) {
  const float* X = (const float*)d_in[0];
  const float* W = (const float*)d_in[1];
  const float* b = (const float*)d_in[2];
  const float* alpha = (const float*)d_in[3];
  const int* ei = (const int*)d_in[4];
  const int* eli = (const int*)d_in[5];
  int N = in_sizes[0] / NFEAT;
  int E = in_sizes[4] / 2;
  int L = in_sizes[5] / 2;
  const int* rowp = ei;
  const int* colp = ei + E;
  const int* lsrc = eli;
  const int* ldst = eli + L;
  float* out = (float*)d_out;

  char* ws = (char*)d_ws;
  size_t off = 0;
  auto alloc = [&](size_t bytes) -> void* {
    void* p = ws + off;
    off += (bytes + 255) & ~(size_t)255;
    return p;
  };
  int* deg = (int*)alloc((size_t)N * 4);
  int* offs = (int*)alloc((size_t)N * 4);
  int* cursor = (int*)alloc((size_t)N * 4);
  int* bsum = (int*)alloc(1024);
  float* dis = (float*)alloc((size_t)N * 4);
  int2* csr = (int2*)alloc((size_t)(E + 16) * 8);
  __half* xa = (__half*)alloc((size_t)N * EDIM * 2);
  __half* xb = (__half*)alloc((size_t)N * EDIM * 2);
  __half* xc = (__half*)alloc((size_t)N * EDIM * 2);
  __half* oacc = (__half*)alloc((size_t)N * EDIM * 2);
  (void)ws_size;
  (void)n_in;
  (void)out_size;

  (void)hipMemsetAsync(deg, 0, (size_t)N * 4, stream);
  hist_kernel<<<2048, 256, 0, stream>>>(colp, deg, E);
  int nb = (N + 1023) / 1024;
  scan1_kernel<<<nb, 256, 0, stream>>>(deg, offs, bsum, N);
  scan2_kernel<<<1, 256, 0, stream>>>(bsum, nb);
  finalize_kernel<<<(N + 255) / 256, 256, 0, stream>>>(offs, cursor, deg, dis, bsum, N);
  fill_kernel<<<2048, 256, 0, stream>>>(rowp, colp, cursor, csr, dis, E);
  embed_kernel<<<(N + 63) / 64, 256, 0, stream>>>(X, W, b, xa, N);
  // chain #1 (measurement duplicate; idempotent)
  prop_kernel<<<2048, 256, 0, stream>>>(xa, xb, oacc, offs, deg, csr, dis, alpha, 0, 0, N);
  prop_kernel<<<2048, 256, 0, stream>>>(xb, xc, oacc, offs, deg, csr, dis, alpha, 1, 0, N);
  prop_kernel<<<2048, 256, 0, stream>>>(xc, xb, oacc, offs, deg, csr, dis, alpha, 2, 1, N);
  // chain #2 (authoritative)
  prop_kernel<<<2048, 256, 0, stream>>>(xa, xb, oacc, offs, deg, csr, dis, alpha, 0, 0, N);
  prop_kernel<<<2048, 256, 0, stream>>>(xb, xc, oacc, offs, deg, csr, dis, alpha, 1, 0, N);
  prop_kernel<<<2048, 256, 0, stream>>>(xc, xb, oacc, offs, deg, csr, dis, alpha, 2, 1, N);
  gatherout_kernel<<<4096, 256, 0, stream>>>(oacc, lsrc, ldst, out, L);
}